// Round 1
// baseline (569.888 us; speedup 1.0000x reference)
//
#include <hip/hip_runtime.h>
#include <math.h>

#define BS 8
#define NQ 1200
#define NV 19560
#define EMB 256

typedef __bf16 bf16;
typedef bf16 bf16x8 __attribute__((ext_vector_type(8)));
typedef float f32x4 __attribute__((ext_vector_type(4)));

static __device__ __forceinline__ bf16x8 cvt8(float4 a, float4 b) {
    bf16x8 r;
    r[0] = (bf16)a.x; r[1] = (bf16)a.y; r[2] = (bf16)a.z; r[3] = (bf16)a.w;
    r[4] = (bf16)b.x; r[5] = (bf16)b.y; r[6] = (bf16)b.z; r[7] = (bf16)b.w;
    return r;
}

// Pack weight f32 [K=256][N] -> bf16 [N][K=256] (transposed, K-contiguous)
__global__ void pack_k(const float* __restrict__ in, bf16* __restrict__ out, int N) {
    int t = blockIdx.x * 256 + threadIdx.x;
    if (t >= N * 256) return;
    int n = t >> 8, k = t & 255;
    out[t] = (bf16)in[k * N + n];
}

// C[M][N] = bf16(A1 (+A2)) @ Bp + bias (+res). K=256 fixed.
// Wave computes 32 rows x 64 cols; block = 4 waves tiled (4/WN along M, WN along N).
template <int N, bool HAS_A2, bool HAS_RES, bool OUT_BF16>
__global__ __launch_bounds__(256) void gemm_k(
    const float* __restrict__ A1, const float* __restrict__ A2,
    const bf16* __restrict__ Bp, const float* __restrict__ bias,
    const float* __restrict__ res, float* __restrict__ outF, bf16* __restrict__ outB)
{
    constexpr int WN = N / 64;      // waves along N (4 for N=256, 2 for N=128)
    const int tid  = threadIdx.x;
    const int lane = tid & 63;
    const int w    = tid >> 6;
    const int l16  = lane & 15;
    const int qd   = lane >> 4;
    const int row_base = blockIdx.x * (32 * (4 / WN)) + (w / WN) * 32;
    const int col_base = (w % WN) * 64;

    f32x4 acc[2][4];
#pragma unroll
    for (int i = 0; i < 2; i++)
#pragma unroll
        for (int j = 0; j < 4; j++) acc[i][j] = (f32x4){0.f, 0.f, 0.f, 0.f};

#pragma unroll
    for (int k0 = 0; k0 < 256; k0 += 32) {
        bf16x8 af[2];
#pragma unroll
        for (int rt = 0; rt < 2; ++rt) {
            size_t o = (size_t)(row_base + rt * 16 + l16) * EMB + k0 + qd * 8;
            float4 x0 = *(const float4*)(A1 + o);
            float4 x1 = *(const float4*)(A1 + o + 4);
            if (HAS_A2) {
                float4 y0 = *(const float4*)(A2 + o);
                float4 y1 = *(const float4*)(A2 + o + 4);
                x0.x += y0.x; x0.y += y0.y; x0.z += y0.z; x0.w += y0.w;
                x1.x += y1.x; x1.y += y1.y; x1.z += y1.z; x1.w += y1.w;
            }
            af[rt] = cvt8(x0, x1);
        }
        bf16x8 bfr[4];
#pragma unroll
        for (int ct = 0; ct < 4; ++ct)
            bfr[ct] = *(const bf16x8*)(Bp + (size_t)(col_base + ct * 16 + l16) * 256 + k0 + qd * 8);
#pragma unroll
        for (int rt = 0; rt < 2; ++rt)
#pragma unroll
            for (int ct = 0; ct < 4; ++ct)
                acc[rt][ct] = __builtin_amdgcn_mfma_f32_16x16x32_bf16(af[rt], bfr[ct], acc[rt][ct], 0, 0, 0);
    }

#pragma unroll
    for (int rt = 0; rt < 2; ++rt) {
#pragma unroll
        for (int ct = 0; ct < 4; ++ct) {
            int col = col_base + ct * 16 + l16;
            float bb = bias[col];
#pragma unroll
            for (int r = 0; r < 4; ++r) {
                int row = row_base + rt * 16 + qd * 4 + r;
                size_t idx = (size_t)row * N + col;
                float v = acc[rt][ct][r] + bb;
                if (HAS_RES) v += res[idx];
                if (OUT_BF16) outB[idx] = (bf16)v;
                else          outF[idx] = v;
            }
        }
    }
}

// Deformable sampling: one block per (b,q); thread = (head, channel).
__global__ __launch_bounds__(256) void sample_k(
    const bf16* __restrict__ vv, const float* __restrict__ offb,
    const float* __restrict__ attnb, const float* __restrict__ refp,
    const float* __restrict__ lref, float* __restrict__ outb)
{
    const int cH[4] = {92, 46, 23, 12};
    const int cW[4] = {160, 80, 40, 20};
    const int cS[4] = {0, 14720, 18400, 19320};
    int bq = blockIdx.x;
    int b  = bq / NQ;
    int tid = threadIdx.x;
    int h = tid >> 5, d = tid & 31;

    // per-head softmax over 16 logits (redundant across the 32 channel lanes)
    const float* ap = attnb + (size_t)bq * 128 + h * 16;
    float wgt[16];
    float mx = -1e30f;
#pragma unroll
    for (int i = 0; i < 16; i++) { wgt[i] = ap[i]; mx = fmaxf(mx, wgt[i]); }
    float s = 0.f;
#pragma unroll
    for (int i = 0; i < 16; i++) { wgt[i] = __expf(wgt[i] - mx); s += wgt[i]; }
    float inv = 1.f / s;

    const float* rp = refp + (size_t)bq * 8;
    float lrx = lref[(size_t)bq * 16 + h * 2 + 0];
    float lry = lref[(size_t)bq * 16 + h * 2 + 1];
    const float* op = offb + (size_t)bq * 256 + h * 32;

    float acc = 0.f;
#pragma unroll
    for (int lvl = 0; lvl < 4; ++lvl) {
        const int Hh = cH[lvl], Ww = cW[lvl];
        const bf16* vb = vv + ((size_t)b * NV + cS[lvl]) * 256 + h * 32 + d;
        float rx = rp[lvl * 2 + 0], ry = rp[lvl * 2 + 1];
#pragma unroll
        for (int p = 0; p < 4; ++p) {
            float ox = op[lvl * 8 + p * 2 + 0];
            float oy = op[lvl * 8 + p * 2 + 1];
            float lx = rx + ox / (float)Ww + lrx;
            float ly = ry + oy / (float)Hh + lry;
            float px = lx * (float)Ww - 0.5f;
            float py = ly * (float)Hh - 0.5f;
            float x0f = floorf(px), y0f = floorf(py);
            int x0 = (int)x0f, y0 = (int)y0f;
            float wx1 = px - x0f, wx0 = 1.f - wx1;
            float wy1 = py - y0f, wy0 = 1.f - wy1;
            float sm = 0.f;
            if ((unsigned)x0 < (unsigned)Ww) {
                if ((unsigned)y0 < (unsigned)Hh)
                    sm += wx0 * wy0 * (float)vb[((size_t)y0 * Ww + x0) * 256];
                if ((unsigned)(y0 + 1) < (unsigned)Hh)
                    sm += wx0 * wy1 * (float)vb[((size_t)(y0 + 1) * Ww + x0) * 256];
            }
            if ((unsigned)(x0 + 1) < (unsigned)Ww) {
                if ((unsigned)y0 < (unsigned)Hh)
                    sm += wx1 * wy0 * (float)vb[((size_t)y0 * Ww + x0 + 1) * 256];
                if ((unsigned)(y0 + 1) < (unsigned)Hh)
                    sm += wx1 * wy1 * (float)vb[((size_t)(y0 + 1) * Ww + x0 + 1) * 256];
            }
            acc += wgt[lvl * 4 + p] * inv * sm;
        }
    }
    outb[(size_t)bq * 256 + tid] = acc;
}

extern "C" void kernel_launch(void* const* d_in, const int* in_sizes, int n_in,
                              void* d_out, int out_size, void* d_ws, size_t ws_size,
                              hipStream_t stream) {
    (void)in_sizes; (void)n_in; (void)out_size; (void)ws_size;
    const float* query = (const float*)d_in[0];
    const float* value = (const float*)d_in[1];
    const float* qpos  = (const float*)d_in[2];
    const float* refp  = (const float*)d_in[3];
    const float* lref  = (const float*)d_in[4];
    // d_in[5] = spatial_shapes (int64) — compile-time constants, unused
    const float* Wv   = (const float*)d_in[6];
    const float* bv   = (const float*)d_in[7];
    const float* Wo   = (const float*)d_in[8];
    const float* bo   = (const float*)d_in[9];
    const float* Wa   = (const float*)d_in[10];
    const float* ba   = (const float*)d_in[11];
    const float* Wout = (const float*)d_in[12];
    const float* bout = (const float*)d_in[13];

    char* ws = (char*)d_ws;
    bf16*  Wv_p   = (bf16*)(ws + 0);          // 131072 B
    bf16*  Wo_p   = (bf16*)(ws + 131072);     // 131072 B
    bf16*  Wa_p   = (bf16*)(ws + 262144);     //  65536 B
    bf16*  Wout_p = (bf16*)(ws + 327680);     // 131072 B
    float* off_b  = (float*)(ws + 524288);    // 9,830,400 B
    float* attn_b = (float*)(ws + 10354688);  // 4,915,200 B
    float* tsa_b  = (float*)(ws + 15269888);  // 9,830,400 B
    bf16*  v_b    = (bf16*)(ws + 25100288);   // 80,117,760 B (end ~100.4 MB)

    pack_k<<<256, 256, 0, stream>>>(Wv, Wv_p, 256);
    pack_k<<<256, 256, 0, stream>>>(Wo, Wo_p, 256);
    pack_k<<<128, 256, 0, stream>>>(Wa, Wa_p, 128);
    pack_k<<<256, 256, 0, stream>>>(Wout, Wout_p, 256);

    // v = value @ Wv + bv  (bf16 out), M = 156480
    gemm_k<256, false, false, true><<<(BS * NV) / 32, 256, 0, stream>>>(
        value, nullptr, Wv_p, bv, nullptr, nullptr, v_b);
    // off = (query+query_pos) @ Wo + bo, M = 9600
    gemm_k<256, true, false, false><<<(BS * NQ) / 32, 256, 0, stream>>>(
        query, qpos, Wo_p, bo, nullptr, off_b, nullptr);
    // attn logits = (query+query_pos) @ Wa + ba, M = 9600, N = 128
    gemm_k<128, true, false, false><<<(BS * NQ) / 64, 256, 0, stream>>>(
        query, qpos, Wa_p, ba, nullptr, attn_b, nullptr);
    // deformable sampling -> tsa_b
    sample_k<<<BS * NQ, 256, 0, stream>>>(v_b, off_b, attn_b, refp, lref, tsa_b);
    // out = tsa @ Wout + bout + query
    gemm_k<256, false, true, false><<<(BS * NQ) / 32, 256, 0, stream>>>(
        tsa_b, nullptr, Wout_p, bout, query, (float*)d_out, nullptr);
}

// Round 2
// 528.875 us; speedup vs baseline: 1.0775x; 1.0775x over previous
//
#include <hip/hip_runtime.h>
#include <math.h>

#define BS 8
#define NQ 1200
#define NV 19560
#define EMB 256

typedef __bf16 bf16;
typedef bf16 bf16x8 __attribute__((ext_vector_type(8)));
typedef float f32x4 __attribute__((ext_vector_type(4)));

static __device__ __forceinline__ bf16x8 cvt8(float4 a, float4 b) {
    bf16x8 r;
    r[0] = (bf16)a.x; r[1] = (bf16)a.y; r[2] = (bf16)a.z; r[3] = (bf16)a.w;
    r[4] = (bf16)b.x; r[5] = (bf16)b.y; r[6] = (bf16)b.z; r[7] = (bf16)b.w;
    return r;
}

// async 16B global -> LDS (wave-uniform LDS base + lane*16 in HW)
static __device__ __forceinline__ void gl16(const float* g, float* l) {
    __builtin_amdgcn_global_load_lds(
        (const __attribute__((address_space(1))) void*)g,
        (__attribute__((address_space(3))) void*)l, 16, 0, 0);
}

// Pack weight f32 [K=256][N] -> bf16 [N][K=256] (transposed, K-contiguous)
__global__ void pack_k(const float* __restrict__ in, bf16* __restrict__ out, int N) {
    int t = blockIdx.x * 256 + threadIdx.x;
    if (t >= N * 256) return;
    int n = t >> 8, k = t & 255;
    out[t] = (bf16)in[k * N + n];
}

// C[M][N] = bf16(A1 (+A2)) @ Bp^T + bias (+res). K=256 fixed.
// Block = 256 thr = 4 waves; tile 64 rows x N cols; wave w owns rows w*16..+15.
// A staged f32 into LDS via global_load_lds with 16B-chunk XOR(row&7) swizzle.
template <int N, bool HAS_A2, bool HAS_RES, bool OUT_BF16>
__global__ __launch_bounds__(256) void gemm2_k(
    const float* __restrict__ A1, const float* __restrict__ A2,
    const bf16* __restrict__ Bp, const float* __restrict__ bias,
    const float* __restrict__ res, float* __restrict__ outF, bf16* __restrict__ outB)
{
    constexpr int CT = N / 16;
    __shared__ __align__(16) float sA[HAS_A2 ? 4096 : 2048]; // 64 rows x 32 f32 (x2)
    const int tid = threadIdx.x;
    const int lane = tid & 63;
    const int w = tid >> 6;
    const int l16 = lane & 15;
    const int qd = lane >> 4;
    const int row0 = blockIdx.x * 64;
    const int r_rd = w * 16 + l16;            // row this lane reads for its A-frag
    const int sw = r_rd & 7;                  // swizzle key (w*16 ≡ 0 mod 8)

    f32x4 acc[CT];
#pragma unroll
    for (int c = 0; c < CT; c++) acc[c] = (f32x4){0.f, 0.f, 0.f, 0.f};

    for (int k0 = 0; k0 < 256; k0 += 32) {
        __syncthreads();   // previous iter's LDS reads done before overwrite
        // stage 64x32 f32 (8KB): 2 issues of 256 lanes x 16B; slot s -> (row s>>3,
        // lds-chunk s&7) holds global chunk (s&7)^(row&7)
#pragma unroll
        for (int i = 0; i < 2; i++) {
            int s = i * 256 + tid;
            int r = s >> 3, cp = s & 7, c = cp ^ (r & 7);
            size_t go = (size_t)(row0 + r) * EMB + k0 + c * 4;
            gl16(A1 + go, sA + (size_t)(i * 256 + w * 64) * 4);
            if (HAS_A2) gl16(A2 + go, sA + 2048 + (size_t)(i * 256 + w * 64) * 4);
        }
        __syncthreads();   // drains vmcnt(0): staged data visible

        int c0 = (qd * 2) ^ sw, c1 = (qd * 2 + 1) ^ sw;
        float4 x0 = *(const float4*)(sA + (r_rd * 8 + c0) * 4);
        float4 x1 = *(const float4*)(sA + (r_rd * 8 + c1) * 4);
        if (HAS_A2) {
            float4 y0 = *(const float4*)(sA + 2048 + (r_rd * 8 + c0) * 4);
            float4 y1 = *(const float4*)(sA + 2048 + (r_rd * 8 + c1) * 4);
            x0.x += y0.x; x0.y += y0.y; x0.z += y0.z; x0.w += y0.w;
            x1.x += y1.x; x1.y += y1.y; x1.z += y1.z; x1.w += y1.w;
        }
        bf16x8 af = cvt8(x0, x1);
#pragma unroll
        for (int ct = 0; ct < CT; ++ct) {
            bf16x8 bfr = *(const bf16x8*)(Bp + (size_t)(ct * 16 + l16) * 256 + k0 + qd * 8);
            acc[ct] = __builtin_amdgcn_mfma_f32_16x16x32_bf16(af, bfr, acc[ct], 0, 0, 0);
        }
    }

#pragma unroll
    for (int ct = 0; ct < CT; ++ct) {
        int col = ct * 16 + l16;
        float bb = bias[col];
#pragma unroll
        for (int rg = 0; rg < 4; ++rg) {
            int row = row0 + w * 16 + qd * 4 + rg;
            size_t idx = (size_t)row * N + col;
            float v = acc[ct][rg] + bb;
            if (HAS_RES) v += res[idx];
            if (OUT_BF16) outB[idx] = (bf16)v;
            else          outF[idx] = v;
        }
    }
}

static __device__ __forceinline__ float4 b4f(uint2 u) {
    float4 r;
    r.x = __uint_as_float(u.x << 16);
    r.y = __uint_as_float(u.x & 0xffff0000u);
    r.z = __uint_as_float(u.y << 16);
    r.w = __uint_as_float(u.y & 0xffff0000u);
    return r;
}

// Deformable sampling: one wave per (b,q); lane = (head h = lane>>3, d4 = lane&7),
// 4 channels per thread via 8B loads. Block 256 = 4 queries.
__global__ __launch_bounds__(256) void sample2_k(
    const bf16* __restrict__ vv, const float* __restrict__ offb,
    const float* __restrict__ attnb, const float* __restrict__ refp,
    const float* __restrict__ lref, float* __restrict__ outb)
{
    const int cH[4] = {92, 46, 23, 12};
    const int cW[4] = {160, 80, 40, 20};
    const int cS[4] = {0, 14720, 18400, 19320};
    int bq = blockIdx.x * 4 + (threadIdx.x >> 6);
    int lane = threadIdx.x & 63;
    int h = lane >> 3, d4 = lane & 7;
    int b = bq / NQ;

    const float* ap = attnb + (size_t)bq * 128 + h * 16;
    float wgt[16];
    float mx = -1e30f;
#pragma unroll
    for (int i = 0; i < 16; i++) { wgt[i] = ap[i]; mx = fmaxf(mx, wgt[i]); }
    float s = 0.f;
#pragma unroll
    for (int i = 0; i < 16; i++) { wgt[i] = __expf(wgt[i] - mx); s += wgt[i]; }
    float inv = 1.f / s;

    const float* rp = refp + (size_t)bq * 8;
    float lrx = lref[(size_t)bq * 16 + h * 2 + 0];
    float lry = lref[(size_t)bq * 16 + h * 2 + 1];
    const float* op = offb + (size_t)bq * 256 + h * 32;

    float4 acc = {0.f, 0.f, 0.f, 0.f};
#pragma unroll
    for (int lvl = 0; lvl < 4; ++lvl) {
        const int Hh = cH[lvl], Ww = cW[lvl];
        // element offset of this thread's 4 channels within a pixel row
        const bf16* vb = vv + ((size_t)b * NV + cS[lvl]) * 256 + h * 32 + d4 * 4;
        float rx = rp[lvl * 2 + 0], ry = rp[lvl * 2 + 1];
#pragma unroll
        for (int p = 0; p < 4; ++p) {
            float ox = op[lvl * 8 + p * 2 + 0];
            float oy = op[lvl * 8 + p * 2 + 1];
            float px = (rx + ox / (float)Ww + lrx) * (float)Ww - 0.5f;
            float py = (ry + oy / (float)Hh + lry) * (float)Hh - 0.5f;
            float x0f = floorf(px), y0f = floorf(py);
            int x0 = (int)x0f, y0 = (int)y0f;
            float wx1 = px - x0f, wx0 = 1.f - wx1;
            float wy1 = py - y0f, wy0 = 1.f - wy1;
            float ww = wgt[lvl * 4 + p] * inv;
            float w00 = ww * wx0 * wy0, w01 = ww * wx1 * wy0;
            float w10 = ww * wx0 * wy1, w11 = ww * wx1 * wy1;
            bool xa = (unsigned)x0 < (unsigned)Ww;
            bool xb = (unsigned)(x0 + 1) < (unsigned)Ww;
            bool ya = (unsigned)y0 < (unsigned)Hh;
            bool yb = (unsigned)(y0 + 1) < (unsigned)Hh;
            if (xa && ya) {
                float4 g = b4f(*(const uint2*)(vb + ((size_t)y0 * Ww + x0) * 256));
                acc.x = fmaf(w00, g.x, acc.x); acc.y = fmaf(w00, g.y, acc.y);
                acc.z = fmaf(w00, g.z, acc.z); acc.w = fmaf(w00, g.w, acc.w);
            }
            if (xb && ya) {
                float4 g = b4f(*(const uint2*)(vb + ((size_t)y0 * Ww + x0 + 1) * 256));
                acc.x = fmaf(w01, g.x, acc.x); acc.y = fmaf(w01, g.y, acc.y);
                acc.z = fmaf(w01, g.z, acc.z); acc.w = fmaf(w01, g.w, acc.w);
            }
            if (xa && yb) {
                float4 g = b4f(*(const uint2*)(vb + ((size_t)(y0 + 1) * Ww + x0) * 256));
                acc.x = fmaf(w10, g.x, acc.x); acc.y = fmaf(w10, g.y, acc.y);
                acc.z = fmaf(w10, g.z, acc.z); acc.w = fmaf(w10, g.w, acc.w);
            }
            if (xb && yb) {
                float4 g = b4f(*(const uint2*)(vb + ((size_t)(y0 + 1) * Ww + x0 + 1) * 256));
                acc.x = fmaf(w11, g.x, acc.x); acc.y = fmaf(w11, g.y, acc.y);
                acc.z = fmaf(w11, g.z, acc.z); acc.w = fmaf(w11, g.w, acc.w);
            }
        }
    }
    *(float4*)(outb + (size_t)bq * 256 + h * 32 + d4 * 4) = acc;
}

extern "C" void kernel_launch(void* const* d_in, const int* in_sizes, int n_in,
                              void* d_out, int out_size, void* d_ws, size_t ws_size,
                              hipStream_t stream) {
    (void)in_sizes; (void)n_in; (void)out_size; (void)ws_size;
    const float* query = (const float*)d_in[0];
    const float* value = (const float*)d_in[1];
    const float* qpos  = (const float*)d_in[2];
    const float* refp  = (const float*)d_in[3];
    const float* lref  = (const float*)d_in[4];
    // d_in[5] = spatial_shapes (int64) — compile-time constants, unused
    const float* Wv   = (const float*)d_in[6];
    const float* bv   = (const float*)d_in[7];
    const float* Wo   = (const float*)d_in[8];
    const float* bo   = (const float*)d_in[9];
    const float* Wa   = (const float*)d_in[10];
    const float* ba   = (const float*)d_in[11];
    const float* Wout = (const float*)d_in[12];
    const float* bout = (const float*)d_in[13];

    char* ws = (char*)d_ws;
    bf16*  Wv_p   = (bf16*)(ws + 0);          // 131072 B
    bf16*  Wo_p   = (bf16*)(ws + 131072);     // 131072 B
    bf16*  Wa_p   = (bf16*)(ws + 262144);     //  65536 B
    bf16*  Wout_p = (bf16*)(ws + 327680);     // 131072 B
    float* off_b  = (float*)(ws + 524288);    // 9,830,400 B
    float* attn_b = (float*)(ws + 10354688);  // 4,915,200 B
    float* tsa_b  = (float*)(ws + 15269888);  // 9,830,400 B
    bf16*  v_b    = (bf16*)(ws + 25100288);   // 80,117,760 B (end ~100.4 MB)

    pack_k<<<256, 256, 0, stream>>>(Wv, Wv_p, 256);
    pack_k<<<256, 256, 0, stream>>>(Wo, Wo_p, 256);
    pack_k<<<128, 256, 0, stream>>>(Wa, Wa_p, 128);
    pack_k<<<256, 256, 0, stream>>>(Wout, Wout_p, 256);

    // v = value @ Wv + bv  (bf16 out), M = 156480, 2445 blocks
    gemm2_k<256, false, false, true><<<(BS * NV) / 64, 256, 0, stream>>>(
        value, nullptr, Wv_p, bv, nullptr, nullptr, v_b);
    // off = (query+query_pos) @ Wo + bo, M = 9600, 150 blocks
    gemm2_k<256, true, false, false><<<(BS * NQ) / 64, 256, 0, stream>>>(
        query, qpos, Wo_p, bo, nullptr, off_b, nullptr);
    // attn logits = (query+query_pos) @ Wa + ba, M = 9600, N = 128
    gemm2_k<128, true, false, false><<<(BS * NQ) / 64, 256, 0, stream>>>(
        query, qpos, Wa_p, ba, nullptr, attn_b, nullptr);
    // deformable sampling -> tsa_b (one wave per query, 4 queries per block)
    sample2_k<<<(BS * NQ) / 4, 256, 0, stream>>>(v_b, off_b, attn_b, refp, lref, tsa_b);
    // out = tsa @ Wout + bout + query
    gemm2_k<256, false, true, false><<<(BS * NQ) / 64, 256, 0, stream>>>(
        tsa_b, nullptr, Wout_p, bout, query, (float*)d_out, nullptr);
}

// Round 3
// 525.781 us; speedup vs baseline: 1.0839x; 1.0059x over previous
//
#include <hip/hip_runtime.h>
#include <math.h>

#define BS 8
#define NQ 1200
#define NV 19560
#define EMB 256

typedef __bf16 bf16;
typedef bf16 bf16x8 __attribute__((ext_vector_type(8)));
typedef float f32x4 __attribute__((ext_vector_type(4)));

static __device__ __forceinline__ bf16x8 cvt8(float4 a, float4 b) {
    bf16x8 r;
    r[0] = (bf16)a.x; r[1] = (bf16)a.y; r[2] = (bf16)a.z; r[3] = (bf16)a.w;
    r[4] = (bf16)b.x; r[5] = (bf16)b.y; r[6] = (bf16)b.z; r[7] = (bf16)b.w;
    return r;
}

// async 16B global -> LDS (wave-uniform LDS base + lane*16 in HW)
static __device__ __forceinline__ void gl16(const void* g, void* l) {
    __builtin_amdgcn_global_load_lds(
        (const __attribute__((address_space(1))) void*)g,
        (__attribute__((address_space(3))) void*)l, 16, 0, 0);
}

// Fused prep: pack 4 weights f32 [K=256][N] -> bf16 [N][256], and qsum = bf16(query+qpos).
// Blocks: [0,256) Wv, [256,512) Wo, [512,640) Wa, [640,896) Wout, [896, 10496) qsum.
__global__ __launch_bounds__(256) void prep_k(
    const float* __restrict__ Wv, const float* __restrict__ Wo,
    const float* __restrict__ Wa, const float* __restrict__ Wout,
    const float* __restrict__ query, const float* __restrict__ qpos,
    bf16* __restrict__ Wv_p, bf16* __restrict__ Wo_p,
    bf16* __restrict__ Wa_p, bf16* __restrict__ Wout_p, bf16* __restrict__ qsum)
{
    int bid = blockIdx.x, tid = threadIdx.x;
    if (bid < 896) {
        const float* src; bf16* dst; int N, t0;
        if (bid < 256)      { src = Wv;   dst = Wv_p;   N = 256; t0 = bid * 256; }
        else if (bid < 512) { src = Wo;   dst = Wo_p;   N = 256; t0 = (bid - 256) * 256; }
        else if (bid < 640) { src = Wa;   dst = Wa_p;   N = 128; t0 = (bid - 512) * 256; }
        else                { src = Wout; dst = Wout_p; N = 256; t0 = (bid - 640) * 256; }
        int t = t0 + tid;
        int n = t >> 8, k = t & 255;
        dst[t] = (bf16)src[k * N + n];
    } else {
        int t = (bid - 896) * 256 + tid;
        qsum[t] = (bf16)(query[t] + qpos[t]);
    }
}

// GEMM: C[M][NS] = bf16(A) @ Bp^T (+bias)(+res). K=256.
// Block = 4 waves, tile = 64 rows x NB cols; even/odd blocks take col halves.
// B half staged ONCE in LDS (<=64KB, XOR-swizzled); A direct to regs, 2-tile pipeline.
// Persistent grid: tile = blockIdx>>1, stride gridDim>>1. No barriers in main loop.
template <int NS, int NB, bool A_F32, bool HAS_RES, bool OUT_BF16>
__global__ __launch_bounds__(256, 2) void gemm3_k(
    const void* __restrict__ Av, const bf16* __restrict__ Bp,
    const float* __restrict__ bias, const float* __restrict__ res,
    float* __restrict__ outF, bf16* __restrict__ outB, int Mtiles)
{
    constexpr int CT = NB / 16;
    __shared__ __align__(16) bf16 sB[NB * 256];   // NB=128 -> 64KB, NB=64 -> 32KB
    const int tid = threadIdx.x;
    const int lane = tid & 63;
    const int w = tid >> 6;
    const int l16 = lane & 15;
    const int qd = lane >> 4;
    const int col0 = (blockIdx.x & 1) * NB;
    const int tstride = gridDim.x >> 1;
    const bf16* Bsrc = Bp + (size_t)col0 * 256;

    float4 curF[16], nxtF[16];
    uint4  curH[8],  nxtH[8];

    auto loadA = [&](int t, float4* dF, uint4* dH) {
        size_t rb = ((size_t)t * 64 + w * 16 + l16) * 256;
        if constexpr (A_F32) {
            const float* A1 = (const float*)Av;
#pragma unroll
            for (int kc = 0; kc < 8; ++kc) {
                dF[2 * kc]     = *(const float4*)(A1 + rb + kc * 32 + qd * 8);
                dF[2 * kc + 1] = *(const float4*)(A1 + rb + kc * 32 + qd * 8 + 4);
            }
        } else {
            const bf16* Ah = (const bf16*)Av;
#pragma unroll
            for (int kc = 0; kc < 8; ++kc)
                dH[kc] = *(const uint4*)(Ah + rb + kc * 32 + qd * 8);
        }
    };

    int tile = blockIdx.x >> 1;
    if (tile < Mtiles) loadA(tile, curF, curH);

    // stage B half: NB rows x 32 chunks of 16B; LDS slot s=(r,p) holds global chunk p^(r&7)
#pragma unroll
    for (int i = 0; i < NB * 32 / 256; ++i) {
        int s = i * 256 + tid;
        int r = s >> 5, p = s & 31, c = p ^ (r & 7);
        gl16(Bsrc + (size_t)r * 256 + c * 8, sB + (size_t)(i * 256 + w * 64) * 8);
    }
    __syncthreads();   // one-time drain: B (and first A) visible

    for (; tile < Mtiles; tile += tstride) {
        int nt = tile + tstride;
        if (nt < Mtiles) loadA(nt, nxtF, nxtH);

        f32x4 acc[CT];
#pragma unroll
        for (int c = 0; c < CT; ++c) acc[c] = (f32x4){0.f, 0.f, 0.f, 0.f};

#pragma unroll
        for (int kc = 0; kc < 8; ++kc) {
            bf16x8 af;
            if constexpr (A_F32) af = cvt8(curF[2 * kc], curF[2 * kc + 1]);
            else                 af = *(const bf16x8*)&curH[kc];
#pragma unroll
            for (int ct = 0; ct < CT; ++ct) {
                int brow = ct * 16 + l16;
                int chunk = (kc * 4 + qd) ^ (l16 & 7);
                bf16x8 bfr = *(const bf16x8*)(sB + (size_t)brow * 256 + chunk * 8);
                acc[ct] = __builtin_amdgcn_mfma_f32_16x16x32_bf16(af, bfr, acc[ct], 0, 0, 0);
            }
        }

#pragma unroll
        for (int ct = 0; ct < CT; ++ct) {
            int col = col0 + ct * 16 + l16;
            float bb = bias[col];
#pragma unroll
            for (int r = 0; r < 4; ++r) {
                int row = tile * 64 + w * 16 + qd * 4 + r;
                size_t idx = (size_t)row * NS + col;
                float v = acc[ct][r] + bb;
                if (HAS_RES) v += res[idx];
                if (OUT_BF16) outB[idx] = (bf16)v;
                else          outF[idx] = v;
            }
        }

        if constexpr (A_F32) {
#pragma unroll
            for (int i = 0; i < 16; ++i) curF[i] = nxtF[i];
        } else {
#pragma unroll
            for (int i = 0; i < 8; ++i) curH[i] = nxtH[i];
        }
    }
}

static __device__ __forceinline__ void b8f(uint4 u, float* f) {
    f[0] = __uint_as_float(u.x << 16); f[1] = __uint_as_float(u.x & 0xffff0000u);
    f[2] = __uint_as_float(u.y << 16); f[3] = __uint_as_float(u.y & 0xffff0000u);
    f[4] = __uint_as_float(u.z << 16); f[5] = __uint_as_float(u.z & 0xffff0000u);
    f[6] = __uint_as_float(u.w << 16); f[7] = __uint_as_float(u.w & 0xffff0000u);
}

// Deformable sampling: thread = (query q, head h, 8-channel group dg). 16B gathers.
// Block 256 threads = 8 queries. Output tsa in bf16.
__global__ __launch_bounds__(256) void sample3_k(
    const bf16* __restrict__ vv, const float* __restrict__ offb,
    const float* __restrict__ attnb, const float* __restrict__ refp,
    const float* __restrict__ lref, bf16* __restrict__ outb)
{
    const int cH[4] = {92, 46, 23, 12};
    const int cW[4] = {160, 80, 40, 20};
    const int cS[4] = {0, 14720, 18400, 19320};
    int tid = threadIdx.x;
    int ql = tid >> 5;
    int l32 = tid & 31;
    int h = l32 >> 2, dg = l32 & 3;
    int bq = blockIdx.x * 8 + ql;
    int b = bq / NQ;

    const float* ap = attnb + (size_t)bq * 128 + h * 16;
    float wgt[16];
    float mx = -1e30f;
#pragma unroll
    for (int i = 0; i < 16; i++) { wgt[i] = ap[i]; mx = fmaxf(mx, wgt[i]); }
    float s = 0.f;
#pragma unroll
    for (int i = 0; i < 16; i++) { wgt[i] = __expf(wgt[i] - mx); s += wgt[i]; }
    float inv = 1.f / s;

    const float* rp = refp + (size_t)bq * 8;
    float lrx = lref[(size_t)bq * 16 + h * 2 + 0];
    float lry = lref[(size_t)bq * 16 + h * 2 + 1];
    const float* op = offb + (size_t)bq * 256 + h * 32;

    float acc[8] = {0.f, 0.f, 0.f, 0.f, 0.f, 0.f, 0.f, 0.f};
#pragma unroll
    for (int lvl = 0; lvl < 4; ++lvl) {
        const int Hh = cH[lvl], Ww = cW[lvl];
        const bf16* vb = vv + ((size_t)b * NV + cS[lvl]) * 256 + h * 32 + dg * 8;
        float rx = rp[lvl * 2 + 0], ry = rp[lvl * 2 + 1];
#pragma unroll
        for (int p = 0; p < 4; ++p) {
            float ox = op[lvl * 8 + p * 2 + 0];
            float oy = op[lvl * 8 + p * 2 + 1];
            float px = (rx + ox / (float)Ww + lrx) * (float)Ww - 0.5f;
            float py = (ry + oy / (float)Hh + lry) * (float)Hh - 0.5f;
            float x0f = floorf(px), y0f = floorf(py);
            int x0 = (int)x0f, y0 = (int)y0f;
            float wx1 = px - x0f, wx0 = 1.f - wx1;
            float wy1 = py - y0f, wy0 = 1.f - wy1;
            float ww = wgt[lvl * 4 + p] * inv;
            float w00 = ww * wx0 * wy0, w01 = ww * wx1 * wy0;
            float w10 = ww * wx0 * wy1, w11 = ww * wx1 * wy1;
            bool xa = (unsigned)x0 < (unsigned)Ww;
            bool xb = (unsigned)(x0 + 1) < (unsigned)Ww;
            bool ya = (unsigned)y0 < (unsigned)Hh;
            bool yb = (unsigned)(y0 + 1) < (unsigned)Hh;
            float f[8];
            if (xa && ya) {
                b8f(*(const uint4*)(vb + ((size_t)y0 * Ww + x0) * 256), f);
#pragma unroll
                for (int j = 0; j < 8; j++) acc[j] = fmaf(w00, f[j], acc[j]);
            }
            if (xb && ya) {
                b8f(*(const uint4*)(vb + ((size_t)y0 * Ww + x0 + 1) * 256), f);
#pragma unroll
                for (int j = 0; j < 8; j++) acc[j] = fmaf(w01, f[j], acc[j]);
            }
            if (xa && yb) {
                b8f(*(const uint4*)(vb + ((size_t)(y0 + 1) * Ww + x0) * 256), f);
#pragma unroll
                for (int j = 0; j < 8; j++) acc[j] = fmaf(w10, f[j], acc[j]);
            }
            if (xb && yb) {
                b8f(*(const uint4*)(vb + ((size_t)(y0 + 1) * Ww + x0 + 1) * 256), f);
#pragma unroll
                for (int j = 0; j < 8; j++) acc[j] = fmaf(w11, f[j], acc[j]);
            }
        }
    }
    bf16x8 o;
#pragma unroll
    for (int j = 0; j < 8; j++) o[j] = (bf16)acc[j];
    *(bf16x8*)(outb + (size_t)bq * 256 + h * 32 + dg * 8) = o;
}

extern "C" void kernel_launch(void* const* d_in, const int* in_sizes, int n_in,
                              void* d_out, int out_size, void* d_ws, size_t ws_size,
                              hipStream_t stream) {
    (void)in_sizes; (void)n_in; (void)out_size; (void)ws_size;
    const float* query = (const float*)d_in[0];
    const float* value = (const float*)d_in[1];
    const float* qpos  = (const float*)d_in[2];
    const float* refp  = (const float*)d_in[3];
    const float* lref  = (const float*)d_in[4];
    // d_in[5] = spatial_shapes (compile-time constants)
    const float* Wv   = (const float*)d_in[6];
    const float* bv   = (const float*)d_in[7];
    const float* Wo   = (const float*)d_in[8];
    const float* bo   = (const float*)d_in[9];
    const float* Wa   = (const float*)d_in[10];
    const float* ba   = (const float*)d_in[11];
    const float* Wout = (const float*)d_in[12];
    const float* bout = (const float*)d_in[13];

    char* ws = (char*)d_ws;
    bf16*  Wv_p   = (bf16*)(ws + 0);          //   131,072
    bf16*  Wo_p   = (bf16*)(ws + 131072);     //   131,072
    bf16*  Wa_p   = (bf16*)(ws + 262144);     //    65,536
    bf16*  Wout_p = (bf16*)(ws + 327680);     //   131,072
    bf16*  qsum   = (bf16*)(ws + 458752);     // 4,915,200
    float* off_b  = (float*)(ws + 5373952);   // 9,830,400
    float* attn_b = (float*)(ws + 15204352);  // 4,915,200
    bf16*  tsa_b  = (bf16*)(ws + 20119552);   // 4,915,200
    bf16*  v_b    = (bf16*)(ws + 25034752);   // 80,117,760 (end ~105 MB)

    prep_k<<<10496, 256, 0, stream>>>(Wv, Wo, Wa, Wout, query, qpos,
                                      Wv_p, Wo_p, Wa_p, Wout_p, qsum);

    // v = value @ Wv + bv (bf16 out): 2445 tiles, persistent 512 blocks
    gemm3_k<256, 128, true, false, true><<<512, 256, 0, stream>>>(
        value, Wv_p, bv, nullptr, nullptr, v_b, (BS * NV) / 64);
    // off = qsum @ Wo + bo (f32): 150 tiles
    gemm3_k<256, 128, false, false, false><<<300, 256, 0, stream>>>(
        qsum, Wo_p, bo, nullptr, off_b, nullptr, (BS * NQ) / 64);
    // attn logits = qsum @ Wa + ba (f32), N=128
    gemm3_k<128, 64, false, false, false><<<300, 256, 0, stream>>>(
        qsum, Wa_p, ba, nullptr, attn_b, nullptr, (BS * NQ) / 64);
    // deformable sampling -> tsa (bf16)
    sample3_k<<<(BS * NQ) / 8, 256, 0, stream>>>(v_b, off_b, attn_b, refp, lref, tsa_b);
    // out = tsa @ Wout + bout + query (f32)
    gemm3_k<256, 128, false, true, false><<<300, 256, 0, stream>>>(
        tsa_b, Wout_p, bout, query, (float*)d_out, nullptr, (BS * NQ) / 64);
}

// Round 5
// 416.682 us; speedup vs baseline: 1.3677x; 1.2618x over previous
//
#include <hip/hip_runtime.h>
#include <math.h>

#define BS 8
#define NQ 1200
#define NV 19560
#define EMB 256

typedef __bf16 bf16;
typedef bf16 bf16x8 __attribute__((ext_vector_type(8)));
typedef float f32x4 __attribute__((ext_vector_type(4)));
typedef float f32x16 __attribute__((ext_vector_type(16)));

static __device__ __forceinline__ bf16x8 cvt8(float4 a, float4 b) {
    bf16x8 r;
    r[0] = (bf16)a.x; r[1] = (bf16)a.y; r[2] = (bf16)a.z; r[3] = (bf16)a.w;
    r[4] = (bf16)b.x; r[5] = (bf16)b.y; r[6] = (bf16)b.z; r[7] = (bf16)b.w;
    return r;
}

// async 16B global -> LDS (wave-uniform LDS base + lane*16 in HW)
static __device__ __forceinline__ void gl16(const void* g, void* l) {
    __builtin_amdgcn_global_load_lds(
        (const __attribute__((address_space(1))) void*)g,
        (__attribute__((address_space(3))) void*)l, 16, 0, 0);
}

// Fused prep: pack 4 weights f32 [K=256][N] -> bf16 [N][256], and qsum = bf16(query+qpos).
__global__ __launch_bounds__(256) void prep_k(
    const float* __restrict__ Wv, const float* __restrict__ Wo,
    const float* __restrict__ Wa, const float* __restrict__ Wout,
    const float* __restrict__ query, const float* __restrict__ qpos,
    bf16* __restrict__ Wv_p, bf16* __restrict__ Wo_p,
    bf16* __restrict__ Wa_p, bf16* __restrict__ Wout_p, bf16* __restrict__ qsum)
{
    int bid = blockIdx.x, tid = threadIdx.x;
    if (bid < 896) {
        const float* src; bf16* dst; int N, t0;
        if (bid < 256)      { src = Wv;   dst = Wv_p;   N = 256; t0 = bid * 256; }
        else if (bid < 512) { src = Wo;   dst = Wo_p;   N = 256; t0 = (bid - 256) * 256; }
        else if (bid < 640) { src = Wa;   dst = Wa_p;   N = 128; t0 = (bid - 512) * 256; }
        else                { src = Wout; dst = Wout_p; N = 256; t0 = (bid - 640) * 256; }
        int t = t0 + tid;
        int n = t >> 8, k = t & 255;
        dst[t] = (bf16)src[k * N + n];
    } else {
        int t = (bid - 896) * 256 + tid;
        qsum[t] = (bf16)(query[t] + qpos[t]);
    }
}

// v-GEMM: C[M][256] = bf16(A_f32) @ Bp^T + bias, bf16 out. K=256, M=Mtiles*64.
// Persistent: 256 blocks, 128KB LDS holds ALL of B (staged once). Tile = 64r x 256c.
// Waves 2x2: each 32 rows x 128 cols, mfma 32x32x16. A global->reg, tile ping-pong.
// No barriers in main loop; A fetched exactly once from HBM.
__global__ __launch_bounds__(256, 1) void vgemm_k(
    const float* __restrict__ A, const bf16* __restrict__ Bp,
    const float* __restrict__ bias, bf16* __restrict__ outB, int Mtiles)
{
    __shared__ __align__(16) bf16 sB[256 * 256];   // 128 KB
    const int tid = threadIdx.x;
    const int lane = tid & 63;
    const int w = tid >> 6;
    const int l32 = lane & 31;
    const int hi = lane >> 5;
    const int wr = w >> 1, wc = w & 1;
    const int tstride = gridDim.x;

    float4 buf0[32], buf1[32];
    auto loadA = [&](int t, float4* d) {
        const float* src = A + ((size_t)t * 64 + wr * 32 + l32) * 256 + hi * 8;
#pragma unroll
        for (int ks = 0; ks < 16; ++ks) {
            d[2 * ks]     = *(const float4*)(src + ks * 16);
            d[2 * ks + 1] = *(const float4*)(src + ks * 16 + 4);
        }
    };

    int t0 = blockIdx.x;
    loadA(t0, buf0);

    // stage ALL of B: 256 rows x 32 chunks of 16B; slot (r,p) holds chunk p^(r&7)
#pragma unroll
    for (int i = 0; i < 32; ++i) {
        int s = i * 256 + tid;
        int r = s >> 5, p = s & 31, c = p ^ (r & 7);
        gl16(Bp + (size_t)r * 256 + c * 8, sB + ((size_t)i * 256 + w * 64) * 8);
    }

    float bb[4];
#pragma unroll
    for (int ct = 0; ct < 4; ++ct) bb[ct] = bias[wc * 128 + ct * 32 + l32];

    __syncthreads();   // drains staging (and first A prefetch)

    auto comp = [&](int t, const float4* d) {
        f32x16 acc[4];
#pragma unroll
        for (int ct = 0; ct < 4; ++ct)
#pragma unroll
            for (int rg = 0; rg < 16; ++rg) acc[ct][rg] = 0.f;
#pragma unroll
        for (int ks = 0; ks < 16; ++ks) {
            bf16x8 af = cvt8(d[2 * ks], d[2 * ks + 1]);
            int p = (ks * 2 + hi) ^ (l32 & 7);
#pragma unroll
            for (int ct = 0; ct < 4; ++ct) {
                int r = wc * 128 + ct * 32 + l32;   // FIX: include wave-column offset
                bf16x8 bfr = *(const bf16x8*)(sB + (size_t)r * 256 + p * 8);
                acc[ct] = __builtin_amdgcn_mfma_f32_32x32x16_bf16(af, bfr, acc[ct], 0, 0, 0);
            }
        }
#pragma unroll
        for (int ct = 0; ct < 4; ++ct) {
            int col = wc * 128 + ct * 32 + l32;
#pragma unroll
            for (int rg = 0; rg < 16; ++rg) {
                int row = t * 64 + wr * 32 + (rg & 3) + 8 * (rg >> 2) + 4 * hi;
                outB[(size_t)row * 256 + col] = (bf16)(acc[ct][rg] + bb[ct]);
            }
        }
    };

    int t = t0;
    while (t < Mtiles) {
        int t1 = t + tstride;
        if (t1 < Mtiles) loadA(t1, buf1);
        comp(t, buf0);
        if (t1 >= Mtiles) break;
        int t2 = t1 + tstride;
        if (t2 < Mtiles) loadA(t2, buf0);
        comp(t1, buf1);
        if (t2 >= Mtiles) break;
        t = t2;
    }
}

// Small GEMM (M=9600): C = bf16A @ Bp^T (+bias)(+res). K=256. Split-N pairs,
// B half in LDS staged once, A direct-to-reg 2-tile pipeline.
template <int NS, int NB, bool HAS_RES, bool OUT_BF16>
__global__ __launch_bounds__(256, 2) void gemm3_k(
    const bf16* __restrict__ Ah, const bf16* __restrict__ Bp,
    const float* __restrict__ bias, const float* __restrict__ res,
    float* __restrict__ outF, bf16* __restrict__ outB, int Mtiles)
{
    constexpr int CT = NB / 16;
    __shared__ __align__(16) bf16 sB[NB * 256];
    const int tid = threadIdx.x;
    const int lane = tid & 63;
    const int w = tid >> 6;
    const int l16 = lane & 15;
    const int qd = lane >> 4;
    const int col0 = (blockIdx.x & 1) * NB;
    const int tstride = gridDim.x >> 1;
    const bf16* Bsrc = Bp + (size_t)col0 * 256;

    uint4 curH[8], nxtH[8];
    auto loadA = [&](int t, uint4* dH) {
        size_t rb = ((size_t)t * 64 + w * 16 + l16) * 256;
#pragma unroll
        for (int kc = 0; kc < 8; ++kc)
            dH[kc] = *(const uint4*)(Ah + rb + kc * 32 + qd * 8);
    };

    int tile = blockIdx.x >> 1;
    if (tile < Mtiles) loadA(tile, curH);

#pragma unroll
    for (int i = 0; i < NB * 32 / 256; ++i) {
        int s = i * 256 + tid;
        int r = s >> 5, p = s & 31, c = p ^ (r & 7);
        gl16(Bsrc + (size_t)r * 256 + c * 8, sB + (size_t)(i * 256 + w * 64) * 8);
    }
    __syncthreads();

    for (; tile < Mtiles; tile += tstride) {
        int nt = tile + tstride;
        if (nt < Mtiles) loadA(nt, nxtH);

        f32x4 acc[CT];
#pragma unroll
        for (int c = 0; c < CT; ++c) acc[c] = (f32x4){0.f, 0.f, 0.f, 0.f};
#pragma unroll
        for (int kc = 0; kc < 8; ++kc) {
            bf16x8 af = *(const bf16x8*)&curH[kc];
#pragma unroll
            for (int ct = 0; ct < CT; ++ct) {
                int brow = ct * 16 + l16;
                int chunk = (kc * 4 + qd) ^ (l16 & 7);
                bf16x8 bfr = *(const bf16x8*)(sB + (size_t)brow * 256 + chunk * 8);
                acc[ct] = __builtin_amdgcn_mfma_f32_16x16x32_bf16(af, bfr, acc[ct], 0, 0, 0);
            }
        }
#pragma unroll
        for (int ct = 0; ct < CT; ++ct) {
            int col = col0 + ct * 16 + l16;
            float bbv = bias[col];
#pragma unroll
            for (int r = 0; r < 4; ++r) {
                int row = tile * 64 + w * 16 + qd * 4 + r;
                size_t idx = (size_t)row * NS + col;
                float v = acc[ct][r] + bbv;
                if (HAS_RES) v += res[idx];
                if (OUT_BF16) outB[idx] = (bf16)v;
                else          outF[idx] = v;
            }
        }
#pragma unroll
        for (int i = 0; i < 8; ++i) curH[i] = nxtH[i];
    }
}

static __device__ __forceinline__ void b8f(uint4 u, float* f) {
    f[0] = __uint_as_float(u.x << 16); f[1] = __uint_as_float(u.x & 0xffff0000u);
    f[2] = __uint_as_float(u.y << 16); f[3] = __uint_as_float(u.y & 0xffff0000u);
    f[4] = __uint_as_float(u.z << 16); f[5] = __uint_as_float(u.z & 0xffff0000u);
    f[6] = __uint_as_float(u.w << 16); f[7] = __uint_as_float(u.w & 0xffff0000u);
}

// Deformable sampling: thread = (query, head, 8-ch group). 16B gathers, bf16 out.
__global__ __launch_bounds__(256) void sample3_k(
    const bf16* __restrict__ vv, const float* __restrict__ offb,
    const float* __restrict__ attnb, const float* __restrict__ refp,
    const float* __restrict__ lref, bf16* __restrict__ outb)
{
    const int cH[4] = {92, 46, 23, 12};
    const int cW[4] = {160, 80, 40, 20};
    const int cS[4] = {0, 14720, 18400, 19320};
    int tid = threadIdx.x;
    int ql = tid >> 5;
    int l32 = tid & 31;
    int h = l32 >> 2, dg = l32 & 3;
    int bq = blockIdx.x * 8 + ql;
    int b = bq / NQ;

    const float* ap = attnb + (size_t)bq * 128 + h * 16;
    float wgt[16];
    float mx = -1e30f;
#pragma unroll
    for (int i = 0; i < 16; i++) { wgt[i] = ap[i]; mx = fmaxf(mx, wgt[i]); }
    float s = 0.f;
#pragma unroll
    for (int i = 0; i < 16; i++) { wgt[i] = __expf(wgt[i] - mx); s += wgt[i]; }
    float inv = 1.f / s;

    const float* rp = refp + (size_t)bq * 8;
    float lrx = lref[(size_t)bq * 16 + h * 2 + 0];
    float lry = lref[(size_t)bq * 16 + h * 2 + 1];
    const float* op = offb + (size_t)bq * 256 + h * 32;

    float acc[8] = {0.f, 0.f, 0.f, 0.f, 0.f, 0.f, 0.f, 0.f};
#pragma unroll
    for (int lvl = 0; lvl < 4; ++lvl) {
        const int Hh = cH[lvl], Ww = cW[lvl];
        const bf16* vb = vv + ((size_t)b * NV + cS[lvl]) * 256 + h * 32 + dg * 8;
        float rx = rp[lvl * 2 + 0], ry = rp[lvl * 2 + 1];
#pragma unroll
        for (int p = 0; p < 4; ++p) {
            float ox = op[lvl * 8 + p * 2 + 0];
            float oy = op[lvl * 8 + p * 2 + 1];
            float px = (rx + ox / (float)Ww + lrx) * (float)Ww - 0.5f;
            float py = (ry + oy / (float)Hh + lry) * (float)Hh - 0.5f;
            float x0f = floorf(px), y0f = floorf(py);
            int x0 = (int)x0f, y0 = (int)y0f;
            float wx1 = px - x0f, wx0 = 1.f - wx1;
            float wy1 = py - y0f, wy0 = 1.f - wy1;
            float ww = wgt[lvl * 4 + p] * inv;
            float w00 = ww * wx0 * wy0, w01 = ww * wx1 * wy0;
            float w10 = ww * wx0 * wy1, w11 = ww * wx1 * wy1;
            bool xa = (unsigned)x0 < (unsigned)Ww;
            bool xb = (unsigned)(x0 + 1) < (unsigned)Ww;
            bool ya = (unsigned)y0 < (unsigned)Hh;
            bool yb = (unsigned)(y0 + 1) < (unsigned)Hh;
            float f[8];
            if (xa && ya) {
                b8f(*(const uint4*)(vb + ((size_t)y0 * Ww + x0) * 256), f);
#pragma unroll
                for (int j = 0; j < 8; j++) acc[j] = fmaf(w00, f[j], acc[j]);
            }
            if (xb && ya) {
                b8f(*(const uint4*)(vb + ((size_t)y0 * Ww + x0 + 1) * 256), f);
#pragma unroll
                for (int j = 0; j < 8; j++) acc[j] = fmaf(w01, f[j], acc[j]);
            }
            if (xa && yb) {
                b8f(*(const uint4*)(vb + ((size_t)(y0 + 1) * Ww + x0) * 256), f);
#pragma unroll
                for (int j = 0; j < 8; j++) acc[j] = fmaf(w10, f[j], acc[j]);
            }
            if (xb && yb) {
                b8f(*(const uint4*)(vb + ((size_t)(y0 + 1) * Ww + x0 + 1) * 256), f);
#pragma unroll
                for (int j = 0; j < 8; j++) acc[j] = fmaf(w11, f[j], acc[j]);
            }
        }
    }
    bf16x8 o;
#pragma unroll
    for (int j = 0; j < 8; j++) o[j] = (bf16)acc[j];
    *(bf16x8*)(outb + (size_t)bq * 256 + h * 32 + dg * 8) = o;
}

extern "C" void kernel_launch(void* const* d_in, const int* in_sizes, int n_in,
                              void* d_out, int out_size, void* d_ws, size_t ws_size,
                              hipStream_t stream) {
    (void)in_sizes; (void)n_in; (void)out_size; (void)ws_size;
    const float* query = (const float*)d_in[0];
    const float* value = (const float*)d_in[1];
    const float* qpos  = (const float*)d_in[2];
    const float* refp  = (const float*)d_in[3];
    const float* lref  = (const float*)d_in[4];
    const float* Wv   = (const float*)d_in[6];
    const float* bv   = (const float*)d_in[7];
    const float* Wo   = (const float*)d_in[8];
    const float* bo   = (const float*)d_in[9];
    const float* Wa   = (const float*)d_in[10];
    const float* ba   = (const float*)d_in[11];
    const float* Wout = (const float*)d_in[12];
    const float* bout = (const float*)d_in[13];

    char* ws = (char*)d_ws;
    bf16*  Wv_p   = (bf16*)(ws + 0);          //   131,072
    bf16*  Wo_p   = (bf16*)(ws + 131072);     //   131,072
    bf16*  Wa_p   = (bf16*)(ws + 262144);     //    65,536
    bf16*  Wout_p = (bf16*)(ws + 327680);     //   131,072
    bf16*  qsum   = (bf16*)(ws + 458752);     // 4,915,200
    float* off_b  = (float*)(ws + 5373952);   // 9,830,400
    float* attn_b = (float*)(ws + 15204352);  // 4,915,200
    bf16*  tsa_b  = (bf16*)(ws + 20119552);   // 4,915,200
    bf16*  v_b    = (bf16*)(ws + 25034752);   // 80,117,760 (end ~105 MB)

    prep_k<<<10496, 256, 0, stream>>>(Wv, Wo, Wa, Wout, query, qpos,
                                      Wv_p, Wo_p, Wa_p, Wout_p, qsum);

    // v = value @ Wv + bv (bf16 out): 2445 tiles over 256 persistent blocks
    vgemm_k<<<256, 256, 0, stream>>>(value, Wv_p, bv, v_b, (BS * NV) / 64);
    // off = qsum @ Wo + bo (f32): 150 tiles
    gemm3_k<256, 128, false, false><<<300, 256, 0, stream>>>(
        qsum, Wo_p, bo, nullptr, off_b, nullptr, (BS * NQ) / 64);
    // attn logits = qsum @ Wa + ba (f32), N=128
    gemm3_k<128, 64, false, false><<<300, 256, 0, stream>>>(
        qsum, Wa_p, ba, nullptr, attn_b, nullptr, (BS * NQ) / 64);
    // deformable sampling -> tsa (bf16)
    sample3_k<<<(BS * NQ) / 8, 256, 0, stream>>>(v_b, off_b, attn_b, refp, lref, tsa_b);
    // out = tsa @ Wout + bout + query (f32)
    gemm3_k<256, 128, true, false><<<300, 256, 0, stream>>>(
        tsa_b, Wout_p, bout, query, (float*)d_out, nullptr, (BS * NQ) / 64);
}

// Round 6
// 399.003 us; speedup vs baseline: 1.4283x; 1.0443x over previous
//
#include <hip/hip_runtime.h>
#include <math.h>

#define BS 8
#define NQ 1200
#define NV 19560
#define EMB 256

typedef __bf16 bf16;
typedef bf16 bf16x8 __attribute__((ext_vector_type(8)));
typedef float f32x4 __attribute__((ext_vector_type(4)));
typedef float f32x16 __attribute__((ext_vector_type(16)));

static __device__ __forceinline__ bf16x8 cvt8(float4 a, float4 b) {
    bf16x8 r;
    r[0] = (bf16)a.x; r[1] = (bf16)a.y; r[2] = (bf16)a.z; r[3] = (bf16)a.w;
    r[4] = (bf16)b.x; r[5] = (bf16)b.y; r[6] = (bf16)b.z; r[7] = (bf16)b.w;
    return r;
}

// async 16B global -> LDS (wave-uniform LDS base + lane*16 in HW)
static __device__ __forceinline__ void gl16(const void* g, void* l) {
    __builtin_amdgcn_global_load_lds(
        (const __attribute__((address_space(1))) void*)g,
        (__attribute__((address_space(3))) void*)l, 16, 0, 0);
}

// Fused prep: pack 4 weights f32 [K=256][N] -> bf16 [N][256], and qsum = bf16(query+qpos).
__global__ __launch_bounds__(256) void prep_k(
    const float* __restrict__ Wv, const float* __restrict__ Wo,
    const float* __restrict__ Wa, const float* __restrict__ Wout,
    const float* __restrict__ query, const float* __restrict__ qpos,
    bf16* __restrict__ Wv_p, bf16* __restrict__ Wo_p,
    bf16* __restrict__ Wa_p, bf16* __restrict__ Wout_p, bf16* __restrict__ qsum)
{
    int bid = blockIdx.x, tid = threadIdx.x;
    if (bid < 896) {
        const float* src; bf16* dst; int N, t0;
        if (bid < 256)      { src = Wv;   dst = Wv_p;   N = 256; t0 = bid * 256; }
        else if (bid < 512) { src = Wo;   dst = Wo_p;   N = 256; t0 = (bid - 256) * 256; }
        else if (bid < 640) { src = Wa;   dst = Wa_p;   N = 128; t0 = (bid - 512) * 256; }
        else                { src = Wout; dst = Wout_p; N = 256; t0 = (bid - 640) * 256; }
        int t = t0 + tid;
        int n = t >> 8, k = t & 255;
        dst[t] = (bf16)src[k * N + n];
    } else {
        int t = (bid - 896) * 256 + tid;
        qsum[t] = (bf16)(query[t] + qpos[t]);
    }
}

// v-GEMM: C[M][256] = bf16(A_f32) @ Bp^T + bias, bf16 out. K=256, M=Mtiles*64.
// Persistent: 256 blocks, 128KB LDS holds ALL of B (staged once). Tile = 64r x 256c.
// Waves 2x2: each 32 rows x 128 cols, mfma 32x32x16. A global->reg, tile ping-pong.
__global__ __launch_bounds__(256, 1) void vgemm_k(
    const float* __restrict__ A, const bf16* __restrict__ Bp,
    const float* __restrict__ bias, bf16* __restrict__ outB, int Mtiles)
{
    __shared__ __align__(16) bf16 sB[256 * 256];   // 128 KB
    const int tid = threadIdx.x;
    const int lane = tid & 63;
    const int w = tid >> 6;
    const int l32 = lane & 31;
    const int hi = lane >> 5;
    const int wr = w >> 1, wc = w & 1;
    const int tstride = gridDim.x;

    float4 buf0[32], buf1[32];
    auto loadA = [&](int t, float4* d) {
        const float* src = A + ((size_t)t * 64 + wr * 32 + l32) * 256 + hi * 8;
#pragma unroll
        for (int ks = 0; ks < 16; ++ks) {
            d[2 * ks]     = *(const float4*)(src + ks * 16);
            d[2 * ks + 1] = *(const float4*)(src + ks * 16 + 4);
        }
    };

    int t0 = blockIdx.x;
    loadA(t0, buf0);

    // stage ALL of B: 256 rows x 32 chunks of 16B; slot (r,p) holds chunk p^(r&7)
#pragma unroll
    for (int i = 0; i < 32; ++i) {
        int s = i * 256 + tid;
        int r = s >> 5, p = s & 31, c = p ^ (r & 7);
        gl16(Bp + (size_t)r * 256 + c * 8, sB + ((size_t)i * 256 + w * 64) * 8);
    }

    float bb[4];
#pragma unroll
    for (int ct = 0; ct < 4; ++ct) bb[ct] = bias[wc * 128 + ct * 32 + l32];

    __syncthreads();   // drains staging (and first A prefetch)

    auto comp = [&](int t, const float4* d) {
        f32x16 acc[4];
#pragma unroll
        for (int ct = 0; ct < 4; ++ct)
#pragma unroll
            for (int rg = 0; rg < 16; ++rg) acc[ct][rg] = 0.f;
#pragma unroll
        for (int ks = 0; ks < 16; ++ks) {
            bf16x8 af = cvt8(d[2 * ks], d[2 * ks + 1]);
            int p = (ks * 2 + hi) ^ (l32 & 7);
#pragma unroll
            for (int ct = 0; ct < 4; ++ct) {
                int r = wc * 128 + ct * 32 + l32;
                bf16x8 bfr = *(const bf16x8*)(sB + (size_t)r * 256 + p * 8);
                acc[ct] = __builtin_amdgcn_mfma_f32_32x32x16_bf16(af, bfr, acc[ct], 0, 0, 0);
            }
        }
#pragma unroll
        for (int ct = 0; ct < 4; ++ct) {
            int col = wc * 128 + ct * 32 + l32;
#pragma unroll
            for (int rg = 0; rg < 16; ++rg) {
                int row = t * 64 + wr * 32 + (rg & 3) + 8 * (rg >> 2) + 4 * hi;
                outB[(size_t)row * 256 + col] = (bf16)(acc[ct][rg] + bb[ct]);
            }
        }
    };

    int t = t0;
    while (t < Mtiles) {
        int t1 = t + tstride;
        if (t1 < Mtiles) loadA(t1, buf1);
        comp(t, buf0);
        if (t1 >= Mtiles) break;
        int t2 = t1 + tstride;
        if (t2 < Mtiles) loadA(t2, buf0);
        comp(t1, buf1);
        if (t2 >= Mtiles) break;
        t = t2;
    }
}

// Small GEMM (M=9600): C = bf16A @ Bp^T (+bias)(+res). K=256. Split-N pairs,
// B half in LDS staged once, A direct-to-reg 2-tile pipeline.
template <int NS, int NB, bool HAS_RES, bool OUT_BF16>
__global__ __launch_bounds__(256, 2) void gemm3_k(
    const bf16* __restrict__ Ah, const bf16* __restrict__ Bp,
    const float* __restrict__ bias, const float* __restrict__ res,
    float* __restrict__ outF, bf16* __restrict__ outB, int Mtiles)
{
    constexpr int CT = NB / 16;
    __shared__ __align__(16) bf16 sB[NB * 256];
    const int tid = threadIdx.x;
    const int lane = tid & 63;
    const int w = tid >> 6;
    const int l16 = lane & 15;
    const int qd = lane >> 4;
    const int col0 = (blockIdx.x & 1) * NB;
    const int tstride = gridDim.x >> 1;
    const bf16* Bsrc = Bp + (size_t)col0 * 256;

    uint4 curH[8], nxtH[8];
    auto loadA = [&](int t, uint4* dH) {
        size_t rb = ((size_t)t * 64 + w * 16 + l16) * 256;
#pragma unroll
        for (int kc = 0; kc < 8; ++kc)
            dH[kc] = *(const uint4*)(Ah + rb + kc * 32 + qd * 8);
    };

    int tile = blockIdx.x >> 1;
    if (tile < Mtiles) loadA(tile, curH);

#pragma unroll
    for (int i = 0; i < NB * 32 / 256; ++i) {
        int s = i * 256 + tid;
        int r = s >> 5, p = s & 31, c = p ^ (r & 7);
        gl16(Bsrc + (size_t)r * 256 + c * 8, sB + (size_t)(i * 256 + w * 64) * 8);
    }
    __syncthreads();

    for (; tile < Mtiles; tile += tstride) {
        int nt = tile + tstride;
        if (nt < Mtiles) loadA(nt, nxtH);

        f32x4 acc[CT];
#pragma unroll
        for (int c = 0; c < CT; ++c) acc[c] = (f32x4){0.f, 0.f, 0.f, 0.f};
#pragma unroll
        for (int kc = 0; kc < 8; ++kc) {
            bf16x8 af = *(const bf16x8*)&curH[kc];
#pragma unroll
            for (int ct = 0; ct < CT; ++ct) {
                int brow = ct * 16 + l16;
                int chunk = (kc * 4 + qd) ^ (l16 & 7);
                bf16x8 bfr = *(const bf16x8*)(sB + (size_t)brow * 256 + chunk * 8);
                acc[ct] = __builtin_amdgcn_mfma_f32_16x16x32_bf16(af, bfr, acc[ct], 0, 0, 0);
            }
        }
#pragma unroll
        for (int ct = 0; ct < CT; ++ct) {
            int col = col0 + ct * 16 + l16;
            float bbv = bias[col];
#pragma unroll
            for (int r = 0; r < 4; ++r) {
                int row = tile * 64 + w * 16 + qd * 4 + r;
                size_t idx = (size_t)row * NS + col;
                float v = acc[ct][r] + bbv;
                if (HAS_RES) v += res[idx];
                if (OUT_BF16) outB[idx] = (bf16)v;
                else          outF[idx] = v;
            }
        }
#pragma unroll
        for (int i = 0; i < 8; ++i) curH[i] = nxtH[i];
    }
}

static __device__ __forceinline__ void b8f(uint4 u, float* f) {
    f[0] = __uint_as_float(u.x << 16); f[1] = __uint_as_float(u.x & 0xffff0000u);
    f[2] = __uint_as_float(u.y << 16); f[3] = __uint_as_float(u.y & 0xffff0000u);
    f[4] = __uint_as_float(u.z << 16); f[5] = __uint_as_float(u.z & 0xffff0000u);
    f[6] = __uint_as_float(u.w << 16); f[7] = __uint_as_float(u.w & 0xffff0000u);
}

// Deformable sampling v4: ONE WAVE per (query,head). lane = (point p=lane>>2,
// channel-group dg=lane&3, 8 ch each). Branchless clamped gathers (4 per lane,
// independent), softmax + P-sum via shfl_xor butterflies. bf16 out.
__global__ __launch_bounds__(256) void sample4_k(
    const bf16* __restrict__ vv, const float* __restrict__ offb,
    const float* __restrict__ attnb, const float* __restrict__ refp,
    const float* __restrict__ lref, bf16* __restrict__ outb)
{
    const int cH[4] = {92, 46, 23, 12};
    const int cW[4] = {160, 80, 40, 20};
    const int cS[4] = {0, 14720, 18400, 19320};
    const int w = threadIdx.x >> 6;
    const int lane = threadIdx.x & 63;
    const int wid = blockIdx.x * 4 + w;        // (bq, h)
    const int bq = wid >> 3, h = wid & 7;
    const int b = bq / NQ;
    const int p = lane >> 2, dg = lane & 3;
    const int lvl = p >> 2;

    // softmax over the 16 points of this (q,h): butterfly over p-lanes
    float logit = attnb[(size_t)bq * 128 + h * 16 + p];
    float mx = logit;
#pragma unroll
    for (int s = 4; s < 64; s <<= 1) mx = fmaxf(mx, __shfl_xor(mx, s));
    float e = __expf(logit - mx);
    float ssum = e;
#pragma unroll
    for (int s = 4; s < 64; s <<= 1) ssum += __shfl_xor(ssum, s);
    float wgt = e / ssum;

    const int Hh = cH[lvl], Ww = cW[lvl];
    float ox = offb[(size_t)bq * 256 + h * 32 + p * 2];
    float oy = offb[(size_t)bq * 256 + h * 32 + p * 2 + 1];
    float rx = refp[(size_t)bq * 8 + lvl * 2];
    float ry = refp[(size_t)bq * 8 + lvl * 2 + 1];
    float lrx = lref[(size_t)bq * 16 + h * 2];
    float lry = lref[(size_t)bq * 16 + h * 2 + 1];

    float px = (rx + ox / (float)Ww + lrx) * (float)Ww - 0.5f;
    float py = (ry + oy / (float)Hh + lry) * (float)Hh - 0.5f;
    float x0f = floorf(px), y0f = floorf(py);
    int x0 = (int)x0f, y0 = (int)y0f;
    float wx1 = px - x0f, wx0 = 1.f - wx1;
    float wy1 = py - y0f, wy0 = 1.f - wy1;
    bool xa = (unsigned)x0 < (unsigned)Ww, xb = (unsigned)(x0 + 1) < (unsigned)Ww;
    bool ya = (unsigned)y0 < (unsigned)Hh, yb = (unsigned)(y0 + 1) < (unsigned)Hh;
    int xc0 = min(max(x0, 0), Ww - 1), xc1 = min(max(x0 + 1, 0), Ww - 1);
    int yc0 = min(max(y0, 0), Hh - 1), yc1 = min(max(y0 + 1, 0), Hh - 1);
    float w00 = wgt * wx0 * wy0 * (float)(xa && ya);
    float w01 = wgt * wx1 * wy0 * (float)(xb && ya);
    float w10 = wgt * wx0 * wy1 * (float)(xa && yb);
    float w11 = wgt * wx1 * wy1 * (float)(xb && yb);

    const bf16* vb = vv + ((size_t)b * NV + cS[lvl]) * 256 + h * 32 + dg * 8;
    uint4 g00 = *(const uint4*)(vb + ((size_t)yc0 * Ww + xc0) * 256);
    uint4 g01 = *(const uint4*)(vb + ((size_t)yc0 * Ww + xc1) * 256);
    uint4 g10 = *(const uint4*)(vb + ((size_t)yc1 * Ww + xc0) * 256);
    uint4 g11 = *(const uint4*)(vb + ((size_t)yc1 * Ww + xc1) * 256);

    float acc[8], f[8];
    b8f(g00, f);
#pragma unroll
    for (int j = 0; j < 8; j++) acc[j] = w00 * f[j];
    b8f(g01, f);
#pragma unroll
    for (int j = 0; j < 8; j++) acc[j] = fmaf(w01, f[j], acc[j]);
    b8f(g10, f);
#pragma unroll
    for (int j = 0; j < 8; j++) acc[j] = fmaf(w10, f[j], acc[j]);
    b8f(g11, f);
#pragma unroll
    for (int j = 0; j < 8; j++) acc[j] = fmaf(w11, f[j], acc[j]);

    // sum over the 16 points (p-lanes): butterfly
#pragma unroll
    for (int s = 4; s < 64; s <<= 1)
#pragma unroll
        for (int j = 0; j < 8; j++) acc[j] += __shfl_xor(acc[j], s);

    if (p == 0) {
        bf16x8 o;
#pragma unroll
        for (int j = 0; j < 8; j++) o[j] = (bf16)acc[j];
        *(bf16x8*)(outb + (size_t)bq * 256 + h * 32 + dg * 8) = o;
    }
}

extern "C" void kernel_launch(void* const* d_in, const int* in_sizes, int n_in,
                              void* d_out, int out_size, void* d_ws, size_t ws_size,
                              hipStream_t stream) {
    (void)in_sizes; (void)n_in; (void)out_size; (void)ws_size;
    const float* query = (const float*)d_in[0];
    const float* value = (const float*)d_in[1];
    const float* qpos  = (const float*)d_in[2];
    const float* refp  = (const float*)d_in[3];
    const float* lref  = (const float*)d_in[4];
    const float* Wv   = (const float*)d_in[6];
    const float* bv   = (const float*)d_in[7];
    const float* Wo   = (const float*)d_in[8];
    const float* bo   = (const float*)d_in[9];
    const float* Wa   = (const float*)d_in[10];
    const float* ba   = (const float*)d_in[11];
    const float* Wout = (const float*)d_in[12];
    const float* bout = (const float*)d_in[13];

    char* ws = (char*)d_ws;
    bf16*  Wv_p   = (bf16*)(ws + 0);          //   131,072
    bf16*  Wo_p   = (bf16*)(ws + 131072);     //   131,072
    bf16*  Wa_p   = (bf16*)(ws + 262144);     //    65,536
    bf16*  Wout_p = (bf16*)(ws + 327680);     //   131,072
    bf16*  qsum   = (bf16*)(ws + 458752);     // 4,915,200
    float* off_b  = (float*)(ws + 5373952);   // 9,830,400
    float* attn_b = (float*)(ws + 15204352);  // 4,915,200
    bf16*  tsa_b  = (bf16*)(ws + 20119552);   // 4,915,200
    bf16*  v_b    = (bf16*)(ws + 25034752);   // 80,117,760 (end ~105 MB)

    prep_k<<<10496, 256, 0, stream>>>(Wv, Wo, Wa, Wout, query, qpos,
                                      Wv_p, Wo_p, Wa_p, Wout_p, qsum);

    // v = value @ Wv + bv (bf16 out): 2445 tiles over 256 persistent blocks
    vgemm_k<<<256, 256, 0, stream>>>(value, Wv_p, bv, v_b, (BS * NV) / 64);
    // off = qsum @ Wo + bo (f32): 150 tiles
    gemm3_k<256, 128, false, false><<<300, 256, 0, stream>>>(
        qsum, Wo_p, bo, nullptr, off_b, nullptr, (BS * NQ) / 64);
    // attn logits = qsum @ Wa + ba (f32), N=128
    gemm3_k<128, 64, false, false><<<300, 256, 0, stream>>>(
        qsum, Wa_p, ba, nullptr, attn_b, nullptr, (BS * NQ) / 64);
    // deformable sampling -> tsa (bf16): one wave per (q,h)
    sample4_k<<<(BS * NQ * 8) / 4, 256, 0, stream>>>(v_b, off_b, attn_b, refp, lref, tsa_b);
    // out = tsa @ Wout + bout + query (f32)
    gemm3_k<256, 128, true, false><<<300, 256, 0, stream>>>(
        tsa_b, Wout_p, bout, query, (float*)d_out, nullptr, (BS * NQ) / 64);
}